// Round 4
// baseline (764.315 us; speedup 1.0000x reference)
//
#include <hip/hip_runtime.h>

#define H 128
typedef unsigned short ushort_t;
typedef unsigned int uint_t;
using s16x8 = __attribute__((ext_vector_type(8))) short;
using f32x4 = __attribute__((ext_vector_type(4))) float;

// ---------------------------------------------------------------- bf16 helpers
__device__ __forceinline__ ushort_t f2bf(float x) {  // RNE
  uint_t u = __float_as_uint(x);
  return (ushort_t)((u + 0x7fff + ((u >> 16) & 1)) >> 16);
}
__device__ __forceinline__ float bflo(uint_t u) { return __uint_as_float(u << 16); }
__device__ __forceinline__ float bfhi(uint_t u) { return __uint_as_float(u & 0xffff0000u); }

// ---------------------------------------------------------------- async global->LDS 16B
__device__ __forceinline__ void gload_lds16(const void* g, void* l) {
  __builtin_amdgcn_global_load_lds(
      (const __attribute__((address_space(1))) unsigned int*)(unsigned long long)g,
      (__attribute__((address_space(3))) unsigned int*)(unsigned int)(unsigned long long)l,
      16, 0, 0);
}

// ---------------------------------------------------------------- zero ints
__global__ void zero_i32(int* __restrict__ p, int n) {
  int i = blockIdx.x * blockDim.x + threadIdx.x;
  int s = gridDim.x * blockDim.x;
  for (; i < n; i += s) p[i] = 0;
}

// ---------------------------------------------------------------- fp32 -> bf16 copy
__global__ void cvt_bf16(const float* __restrict__ in, ushort_t* __restrict__ out, size_t n4) {
  size_t i = (size_t)blockIdx.x * blockDim.x + threadIdx.x;
  size_t s = (size_t)gridDim.x * blockDim.x;
  for (; i < n4; i += s) {
    float4 v = ((const float4*)in)[i];
    uint2 r;
    r.x = (uint_t)f2bf(v.x) | ((uint_t)f2bf(v.y) << 16);
    r.y = (uint_t)f2bf(v.z) | ((uint_t)f2bf(v.w) << 16);
    ((uint2*)out)[i] = r;
  }
}

// ------------------------------------------- W pair -> MFMA B-fragment layout
// dst[ks][nf][lane][j]: B[k][n] with k = ks*32 + (lane>>4)*8 + j, n = nf*16 + (lane&15)
__global__ void build_wfrag(const float* __restrict__ Wl, const float* __restrict__ Wr,
                            ushort_t* __restrict__ dst) {
  int i = blockIdx.x * 256 + threadIdx.x;  // 0..32767
  int j = i & 7;
  int lane = (i >> 3) & 63;
  int nf = (i >> 9) & 7;
  int ks = i >> 12;
  int k = ks * 32 + (lane >> 4) * 8 + j;
  int nn = nf * 16 + (lane & 15);
  float v = (k < H) ? Wl[k * H + nn] : Wr[(k - H) * H + nn];
  dst[i] = f2bf(v);
}

// ---------------------------------------------------------------- edge histogram
__global__ void hist_kernel(const int* __restrict__ src, const int* __restrict__ dst,
                            int* __restrict__ cnt_e, int* __restrict__ cnt_t, int E) {
  int i = blockIdx.x * blockDim.x + threadIdx.x;
  int s = gridDim.x * blockDim.x;
  for (; i < E; i += s) {
    atomicAdd(&cnt_t[dst[i]], 1);
    atomicAdd(&cnt_e[src[i]], 1);
  }
}

// ---------------------------------------------------------------- 3-phase exclusive scan
__global__ void scan1(const int* __restrict__ in, int* __restrict__ out,
                      int* __restrict__ part, int n) {
  __shared__ int s[256];
  int t = threadIdx.x;
  int i = blockIdx.x * 256 + t;
  int v = (i < n) ? in[i] : 0;
  s[t] = v;
  __syncthreads();
  for (int off = 1; off < 256; off <<= 1) {
    int tmp = (t >= off) ? s[t - off] : 0;
    __syncthreads();
    s[t] += tmp;
    __syncthreads();
  }
  if (i < n) out[i] = s[t] - v;
  if (t == 255) part[blockIdx.x] = s[255];
}

__global__ void scan2(int* __restrict__ part, int nb) {
  __shared__ int s[256];
  __shared__ int carry;
  int t = threadIdx.x;
  if (t == 0) carry = 0;
  __syncthreads();
  for (int base = 0; base < nb; base += 256) {
    int i = base + t;
    int v = (i < nb) ? part[i] : 0;
    s[t] = v;
    __syncthreads();
    for (int off = 1; off < 256; off <<= 1) {
      int tmp = (t >= off) ? s[t - off] : 0;
      __syncthreads();
      s[t] += tmp;
      __syncthreads();
    }
    if (i < nb) part[i] = s[t] - v + carry;
    __syncthreads();
    if (t == 255) carry += s[255];
    __syncthreads();
  }
}

__global__ void scan3(int* __restrict__ out, const int* __restrict__ part, int n) {
  int i = blockIdx.x * 256 + threadIdx.x;
  if (i < n) out[i] += part[blockIdx.x];
}

// ---------------------------------------------------------------- edge CSR fill
__global__ void fill_kernel(const int* __restrict__ src, const int* __restrict__ dst,
                            const int* __restrict__ off_e, const int* __restrict__ off_t,
                            int* __restrict__ cur_e, int* __restrict__ cur_t,
                            int* __restrict__ adj_e, int* __restrict__ adj_t, int E) {
  int i = blockIdx.x * blockDim.x + threadIdx.x;
  int st = gridDim.x * blockDim.x;
  for (; i < E; i += st) {
    int s = src[i], d = dst[i];
    int pt = off_t[d] + atomicAdd(&cur_t[d], 1);
    adj_t[pt] = s;
    int pe = off_e[s] + atomicAdd(&cur_e[s], 1);
    adj_e[pe] = d;
  }
}

// ---------------------------------------------------------------- label histogram / fill
__global__ void hist_labels(const int* __restrict__ ld, int* __restrict__ cnt, int L) {
  int i = blockIdx.x * blockDim.x + threadIdx.x;
  int s = gridDim.x * blockDim.x;
  for (; i < L; i += s) atomicAdd(&cnt[ld[i]], 1);
}

__global__ void fill_labels(const int* __restrict__ ls, const int* __restrict__ ld,
                            const int* __restrict__ loff, int* __restrict__ cur,
                            int* __restrict__ lperm, int* __restrict__ lsrc, int L) {
  int i = blockIdx.x * blockDim.x + threadIdx.x;
  int st = gridDim.x * blockDim.x;
  for (; i < L; i += st) {
    int d = ld[i];
    int p = loff[d] + atomicAdd(&cur[d], 1);
    lperm[p] = i;
    lsrc[p] = ls[i];
  }
}

// ---------------------------------------------------------------- fused pull-mean + MFMA GEMM
// out[row,:] = act( [mean_{u in adj(row)} gfeat[u,:] | xd[row,:]] @ [Wl;Wr] + bias )
// K=256, N=128, bf16 in/out, fp32 accum. B entirely in registers.
template <bool RELU>
__global__ __launch_bounds__(256, 2) void fused_layer(
    const ushort_t* __restrict__ gfeat, const int* __restrict__ off,
    const int* __restrict__ adj, const ushort_t* __restrict__ xd,
    const ushort_t* __restrict__ wfrag, const float* __restrict__ bias,
    ushort_t* __restrict__ out, int n) {
  __shared__ __align__(16) ushort_t sA[64 * 128];  // gathered means (swizzled rows)
  __shared__ __align__(16) ushort_t sX[64 * 128];  // self feats (swizzled rows)
  const int t = threadIdx.x;
  const int lane = t & 63;
  const int wid = t >> 6;
  const int mrow = (wid >> 1) * 32;   // wave's 32 output rows
  const int nhalf = (wid & 1) * 64;   // wave's 64 output cols

  // B fragments in registers: 8 K-steps x 4 N-frags (this wave's 64 cols)
  s16x8 B[8][4];
#pragma unroll
  for (int ks = 0; ks < 8; ++ks)
#pragma unroll
    for (int nfi = 0; nfi < 4; ++nfi)
      B[ks][nfi] = *(const s16x8*)(wfrag + (size_t)(((ks << 3) | ((nhalf >> 4) + nfi)) << 9) + (lane << 3));

  float bv[4];
#pragma unroll
  for (int nfi = 0; nfi < 4; ++nfi) bv[nfi] = bias[nhalf + nfi * 16 + (lane & 15)];

  const int lrow = lane >> 4;
  const int pbyte = (lane & 15) << 4;
  const uint_t* gf = (const uint_t*)gfeat;

  const int ntiles = (n + 63) >> 6;
  for (int tile = blockIdx.x; tile < ntiles; tile += gridDim.x) {
    const int row0 = tile << 6;

    // ---- stage self feats: 16 regions of 4 rows x 256B; this wave does 4
#pragma unroll
    for (int i = 0; i < 4; ++i) {
      int reg = (wid << 2) + i;
      int rr = (reg << 2) + lrow;
      int row = row0 + rr;
      row = row < n ? row : n - 1;
      int pp = pbyte ^ ((rr & 7) << 4);  // pre-swizzled source => swizzled LDS
      gload_lds16(xd + (size_t)row * H + (pp >> 1), sX + ((size_t)reg << 9));
    }

    // ---- gather means for this wave's 16 rows, write swizzled into sA
    for (int r = 0; r < 16; ++r) {
      int rr = (wid << 4) + r;
      int row = row0 + rr;
      float ax0 = 0.f, ay0 = 0.f, ax1 = 0.f, ay1 = 0.f;
      float ax2 = 0.f, ay2 = 0.f, ax3 = 0.f, ay3 = 0.f;
      int s = 0, e = 0;
      if (row < n) { s = off[row]; e = off[row + 1]; }
      int i = s;
      for (; i + 4 <= e; i += 4) {
        uint_t u0 = gf[(size_t)adj[i] * 64 + lane];
        uint_t u1 = gf[(size_t)adj[i + 1] * 64 + lane];
        uint_t u2 = gf[(size_t)adj[i + 2] * 64 + lane];
        uint_t u3 = gf[(size_t)adj[i + 3] * 64 + lane];
        ax0 += bflo(u0); ay0 += bfhi(u0);
        ax1 += bflo(u1); ay1 += bfhi(u1);
        ax2 += bflo(u2); ay2 += bfhi(u2);
        ax3 += bflo(u3); ay3 += bfhi(u3);
      }
      for (; i < e; ++i) {
        uint_t u = gf[(size_t)adj[i] * 64 + lane];
        ax0 += bflo(u); ay0 += bfhi(u);
      }
      float rd = 1.0f / fmaxf((float)(e - s), 1.0f);
      uint_t pr = (uint_t)f2bf(((ax0 + ax1) + (ax2 + ax3)) * rd) |
                  ((uint_t)f2bf(((ay0 + ay1) + (ay2 + ay3)) * rd) << 16);
      *(uint_t*)((char*)sA + (rr << 8) + ((lane << 2) ^ ((rr & 7) << 4))) = pr;
    }
    __syncthreads();

    // ---- MFMA: C[64x128] = A[64x256] @ B[256x128]
    f32x4 acc[2][4];
#pragma unroll
    for (int mi = 0; mi < 2; ++mi)
#pragma unroll
      for (int nfi = 0; nfi < 4; ++nfi) {
        f32x4 c = {bv[nfi], bv[nfi], bv[nfi], bv[nfi]};
        acc[mi][nfi] = c;
      }

    const int rr0 = mrow + (lane & 15);
    const int rr1 = rr0 + 16;
    const int kx = (lane >> 4) << 4;
    const int sw = (rr0 & 7) << 4;
#pragma unroll
    for (int ks = 0; ks < 8; ++ks) {
      const ushort_t* base = (ks < 4) ? sA : sX;
      const int kb = (ks & 3) << 6;
      s16x8 a0 = *(const s16x8*)((const char*)base + rr0 * 256 + ((kb | kx) ^ sw));
      s16x8 a1 = *(const s16x8*)((const char*)base + rr1 * 256 + ((kb | kx) ^ sw));
#pragma unroll
      for (int nfi = 0; nfi < 4; ++nfi) {
        acc[0][nfi] = __builtin_amdgcn_mfma_f32_16x16x32_bf16(a0, B[ks][nfi], acc[0][nfi], 0, 0, 0);
        acc[1][nfi] = __builtin_amdgcn_mfma_f32_16x16x32_bf16(a1, B[ks][nfi], acc[1][nfi], 0, 0, 0);
      }
    }

    // ---- epilogue: C/D layout col = lane&15, row = (lane>>4)*4 + r
#pragma unroll
    for (int mi = 0; mi < 2; ++mi) {
      int rbase = row0 + mrow + mi * 16 + ((lane >> 4) << 2);
#pragma unroll
      for (int r = 0; r < 4; ++r) {
        int row = rbase + r;
        if (row < n) {
#pragma unroll
          for (int nfi = 0; nfi < 4; ++nfi) {
            float v = acc[mi][nfi][r];
            if (RELU) v = fmaxf(v, 0.f);
            out[(size_t)row * H + nhalf + nfi * 16 + (lane & 15)] = f2bf(v);
          }
        }
      }
    }
    __syncthreads();
  }
}

// ---------------------------------------------------------------- grouped edge dot
// one wave per team: z_t row held in registers, gather z_e rows per label.
__global__ void edge_dot_grouped(const ushort_t* __restrict__ ze, const ushort_t* __restrict__ zt,
                                 const int* __restrict__ loff, const int* __restrict__ lperm,
                                 const int* __restrict__ lsrc, float* __restrict__ out, int n_t) {
  int gid = blockIdx.x * blockDim.x + threadIdx.x;
  int wave = gid >> 6;
  int lane = gid & 63;
  int nw = (gridDim.x * blockDim.x) >> 6;
  const uint_t* fz = (const uint_t*)ze;
  const uint_t* ft = (const uint_t*)zt;
  for (int v = wave; v < n_t; v += nw) {
    int s = loff[v], e = loff[v + 1];
    if (s == e) continue;
    uint_t ub = ft[(size_t)v * 64 + lane];
    float blo = bflo(ub), bhi = bfhi(ub);
    int i = s;
    for (; i + 2 <= e; i += 2) {
      int a0 = lsrc[i], a1 = lsrc[i + 1];
      uint_t u0 = fz[(size_t)a0 * 64 + lane];
      uint_t u1 = fz[(size_t)a1 * 64 + lane];
      float p0 = bflo(u0) * blo + bfhi(u0) * bhi;
      float p1 = bflo(u1) * blo + bfhi(u1) * bhi;
#pragma unroll
      for (int o = 32; o; o >>= 1) {
        p0 += __shfl_down(p0, o);
        p1 += __shfl_down(p1, o);
      }
      if (lane == 0) {
        out[lperm[i]] = p0;
        out[lperm[i + 1]] = p1;
      }
    }
    if (i < e) {
      uint_t u0 = fz[(size_t)lsrc[i] * 64 + lane];
      float p0 = bflo(u0) * blo + bfhi(u0) * bhi;
#pragma unroll
      for (int o = 32; o; o >>= 1) p0 += __shfl_down(p0, o);
      if (lane == 0) out[lperm[i]] = p0;
    }
  }
}

// ---------------------------------------------------------------- launch
extern "C" void kernel_launch(void* const* d_in, const int* in_sizes, int n_in,
                              void* d_out, int out_size, void* d_ws, size_t ws_size,
                              hipStream_t stream) {
  const float* x_e = (const float*)d_in[0];
  const float* x_t = (const float*)d_in[1];
  const int* src = (const int*)d_in[2];
  const int* dst = (const int*)d_in[3];
  const int* ls = (const int*)d_in[4];
  const int* ld = (const int*)d_in[5];
  const float* W1et_l = (const float*)d_in[6];
  const float* W1et_r = (const float*)d_in[7];
  const float* W1te_l = (const float*)d_in[8];
  const float* W1te_r = (const float*)d_in[9];
  const float* W2et_l = (const float*)d_in[10];
  const float* W2et_r = (const float*)d_in[11];
  const float* W2te_l = (const float*)d_in[12];
  const float* W2te_r = (const float*)d_in[13];
  const float* b1et = (const float*)d_in[14];
  const float* b1te = (const float*)d_in[15];
  const float* b2et = (const float*)d_in[16];
  const float* b2te = (const float*)d_in[17];

  const int n_e = in_sizes[0] / H;
  const int n_t = in_sizes[1] / H;
  const int E = in_sizes[2];
  const int L = in_sizes[4];
  float* out = (float*)d_out;

  const size_t fe = (size_t)n_e * H;
  const size_t ft = (size_t)n_t * H;
  ushort_t* us = (ushort_t*)d_ws;
  ushort_t* xb_e = us;               // fe
  ushort_t* xb_t = xb_e + fe;        // ft
  ushort_t* h_e = xb_t + ft;         // fe
  ushort_t* h_t = h_e + fe;          // ft
  ushort_t* z_e = h_t + ft;          // fe
  ushort_t* z_t = z_e + fe;          // ft
  ushort_t* wf1et = z_t + ft;        // 32768 each
  ushort_t* wf1te = wf1et + 32768;
  ushort_t* wf2et = wf1te + 32768;
  ushort_t* wf2te = wf2et + 32768;
  int* ib = (int*)(wf2te + 32768);
  int* cnt_t = ib;                  // n_t+1
  int* cnt_e = cnt_t + (n_t + 1);   // n_e+1
  int* off_t = cnt_e + (n_e + 1);   // n_t+1
  int* off_e = off_t + (n_t + 1);   // n_e+1
  int* part = off_e + (n_e + 1);    // 1024
  int* adj_t = part + 1024;         // E
  int* adj_e = adj_t + E;           // E
  // label CSR aliases (used only after layer-2 kernels are done with adj_*)
  int* lperm = adj_t;               // L <= E
  int* loff = adj_e;                // n_t+1
  int* lsrc = adj_e + 65536;        // L

  const dim3 blk(256);

  // ---- bf16 conversions + weight fragments
  cvt_bf16<<<2048, blk, 0, stream>>>(x_e, xb_e, fe / 4);
  cvt_bf16<<<2048, blk, 0, stream>>>(x_t, xb_t, ft / 4);
  build_wfrag<<<128, blk, 0, stream>>>(W1et_l, W1et_r, wf1et);
  build_wfrag<<<128, blk, 0, stream>>>(W1te_l, W1te_r, wf1te);
  build_wfrag<<<128, blk, 0, stream>>>(W2et_l, W2et_r, wf2et);
  build_wfrag<<<128, blk, 0, stream>>>(W2te_l, W2te_r, wf2te);

  // ---- edge CSR build
  zero_i32<<<256, blk, 0, stream>>>(cnt_t, (n_t + 1) + (n_e + 1));
  hist_kernel<<<1024, blk, 0, stream>>>(src, dst, cnt_e, cnt_t, E);
  int nbt = (n_t + 1 + 255) / 256;
  int nbe = (n_e + 1 + 255) / 256;
  scan1<<<nbt, blk, 0, stream>>>(cnt_t, off_t, part, n_t + 1);
  scan2<<<1, blk, 0, stream>>>(part, nbt);
  scan3<<<nbt, blk, 0, stream>>>(off_t, part, n_t + 1);
  scan1<<<nbe, blk, 0, stream>>>(cnt_e, off_e, part, n_e + 1);
  scan2<<<1, blk, 0, stream>>>(part, nbe);
  scan3<<<nbe, blk, 0, stream>>>(off_e, part, n_e + 1);
  zero_i32<<<256, blk, 0, stream>>>(cnt_t, (n_t + 1) + (n_e + 1));
  fill_kernel<<<1024, blk, 0, stream>>>(src, dst, off_e, off_t, cnt_e, cnt_t, adj_e, adj_t, E);

  const int gt = min((n_t + 63) / 64, 512);
  const int ge = min((n_e + 63) / 64, 512);

  // ---- layer 1 (fused pull-mean + GEMM + ReLU)
  fused_layer<true><<<gt, blk, 0, stream>>>(xb_e, off_t, adj_t, xb_t, wf1et, b1et, h_t, n_t);
  fused_layer<true><<<ge, blk, 0, stream>>>(xb_t, off_e, adj_e, xb_e, wf1te, b1te, h_e, n_e);

  // ---- layer 2
  fused_layer<false><<<gt, blk, 0, stream>>>(h_e, off_t, adj_t, h_t, wf2et, b2et, z_t, n_t);
  fused_layer<false><<<ge, blk, 0, stream>>>(h_t, off_e, adj_e, h_e, wf2te, b2te, z_e, n_e);

  // ---- label CSR (aliases onto adj_* which are now dead)
  zero_i32<<<256, blk, 0, stream>>>(cnt_t, n_t + 1);
  hist_labels<<<1024, blk, 0, stream>>>(ld, cnt_t, L);
  scan1<<<nbt, blk, 0, stream>>>(cnt_t, loff, part, n_t + 1);
  scan2<<<1, blk, 0, stream>>>(part, nbt);
  scan3<<<nbt, blk, 0, stream>>>(loff, part, n_t + 1);
  zero_i32<<<256, blk, 0, stream>>>(cnt_t, n_t + 1);
  fill_labels<<<1024, blk, 0, stream>>>(ls, ld, loff, cnt_t, lperm, lsrc, L);

  // ---- grouped edge dot readout
  edge_dot_grouped<<<(n_t + 3) / 4, blk, 0, stream>>>(z_e, z_t, loff, lperm, lsrc, out, n_t);
}

// Round 5
// 465.201 us; speedup vs baseline: 1.6430x; 1.6430x over previous
//
#include <hip/hip_runtime.h>

#define H 128
typedef unsigned short ushort_t;
typedef unsigned int uint_t;
using s16x8 = __attribute__((ext_vector_type(8))) short;
using f32x4 = __attribute__((ext_vector_type(4))) float;

// ---------------------------------------------------------------- bf16 helpers
__device__ __forceinline__ ushort_t f2bf(float x) {  // RNE
  uint_t u = __float_as_uint(x);
  return (ushort_t)((u + 0x7fff + ((u >> 16) & 1)) >> 16);
}
__device__ __forceinline__ float bflo(uint_t u) { return __uint_as_float(u << 16); }
__device__ __forceinline__ float bfhi(uint_t u) { return __uint_as_float(u & 0xffff0000u); }

// ---------------------------------------------------------------- async global->LDS 16B
__device__ __forceinline__ void gload_lds16(const void* g, void* l) {
  __builtin_amdgcn_global_load_lds(
      (const __attribute__((address_space(1))) unsigned int*)(unsigned long long)g,
      (__attribute__((address_space(3))) unsigned int*)(unsigned int)(unsigned long long)l,
      16, 0, 0);
}

// ---------------------------------------------------------------- zero ints
__global__ void zero_i32(int* __restrict__ p, int n) {
  int i = blockIdx.x * blockDim.x + threadIdx.x;
  int s = gridDim.x * blockDim.x;
  for (; i < n; i += s) p[i] = 0;
}

// ---------------------------------------------------------------- fp32 -> bf16 (two srcs, contiguous dst)
__global__ void cvt2_bf16(const float* __restrict__ a, const float* __restrict__ b,
                          size_t n4a, size_t n4tot, uint2* __restrict__ out) {
  size_t i = (size_t)blockIdx.x * blockDim.x + threadIdx.x;
  size_t s = (size_t)gridDim.x * blockDim.x;
  for (; i < n4tot; i += s) {
    float4 v = (i < n4a) ? ((const float4*)a)[i] : ((const float4*)b)[i - n4a];
    uint2 r;
    r.x = (uint_t)f2bf(v.x) | ((uint_t)f2bf(v.y) << 16);
    r.y = (uint_t)f2bf(v.z) | ((uint_t)f2bf(v.w) << 16);
    out[i] = r;
  }
}

// ------------------------------------------- 4 W-pairs -> MFMA B-fragment layout
// per pair: dst[ks][nf][lane][j]: B[k][n], k = ks*32 + (lane>>4)*8 + j, n = nf*16 + (lane&15)
__global__ void build_wfrag4(const float* __restrict__ Wl0, const float* __restrict__ Wr0,
                             const float* __restrict__ Wl1, const float* __restrict__ Wr1,
                             const float* __restrict__ Wl2, const float* __restrict__ Wr2,
                             const float* __restrict__ Wl3, const float* __restrict__ Wr3,
                             ushort_t* __restrict__ dst) {
  int i = blockIdx.x * 256 + threadIdx.x;  // 0..131071
  int w = i >> 15;
  int ii = i & 32767;
  int j = ii & 7;
  int lane = (ii >> 3) & 63;
  int nf = (ii >> 9) & 7;
  int ks = ii >> 12;
  int k = ks * 32 + (lane >> 4) * 8 + j;
  int nn = nf * 16 + (lane & 15);
  const float* Wl = (w == 0) ? Wl0 : (w == 1) ? Wl1 : (w == 2) ? Wl2 : Wl3;
  const float* Wr = (w == 0) ? Wr0 : (w == 1) ? Wr1 : (w == 2) ? Wr2 : Wr3;
  float v = (k < H) ? Wl[k * H + nn] : Wr[(k - H) * H + nn];
  dst[i] = f2bf(v);
}

// ---------------------------------------------------------------- merged histogram (edges + labels)
__global__ void hist_all(const int* __restrict__ src, const int* __restrict__ dst,
                         const int* __restrict__ ld,
                         int* __restrict__ cnt_t, int* __restrict__ cnt_e,
                         int* __restrict__ cnt_l, int E, int L) {
  int i = blockIdx.x * blockDim.x + threadIdx.x;
  int s = gridDim.x * blockDim.x;
  int M = E > L ? E : L;
  for (; i < M; i += s) {
    if (i < E) {
      atomicAdd(&cnt_t[dst[i]], 1);
      atomicAdd(&cnt_e[src[i]], 1);
    }
    if (i < L) atomicAdd(&cnt_l[ld[i]], 1);
  }
}

// ---------------------------------------------------------------- 3-phase exclusive scan
__global__ void scan1(const int* __restrict__ in, int* __restrict__ out,
                      int* __restrict__ part, int n) {
  __shared__ int s[256];
  int t = threadIdx.x;
  int i = blockIdx.x * 256 + t;
  int v = (i < n) ? in[i] : 0;
  s[t] = v;
  __syncthreads();
  for (int off = 1; off < 256; off <<= 1) {
    int tmp = (t >= off) ? s[t - off] : 0;
    __syncthreads();
    s[t] += tmp;
    __syncthreads();
  }
  if (i < n) out[i] = s[t] - v;
  if (t == 255) part[blockIdx.x] = s[255];
}

__global__ void scan2(int* __restrict__ part, int nb) {
  __shared__ int s[256];
  __shared__ int carry;
  int t = threadIdx.x;
  if (t == 0) carry = 0;
  __syncthreads();
  for (int base = 0; base < nb; base += 256) {
    int i = base + t;
    int v = (i < nb) ? part[i] : 0;
    s[t] = v;
    __syncthreads();
    for (int off = 1; off < 256; off <<= 1) {
      int tmp = (t >= off) ? s[t - off] : 0;
      __syncthreads();
      s[t] += tmp;
      __syncthreads();
    }
    if (i < nb) part[i] = s[t] - v + carry;
    __syncthreads();
    if (t == 255) carry += s[255];
    __syncthreads();
  }
}

__global__ void scan3(int* __restrict__ out, const int* __restrict__ part, int n) {
  int i = blockIdx.x * 256 + threadIdx.x;
  if (i < n) out[i] += part[blockIdx.x];
}

// ---------------------------------------------------------------- merged fill (edges + labels)
// uses atomicSub on counts (they end back at zero); bucket order is reversed (irrelevant).
__global__ void fill_all(const int* __restrict__ src, const int* __restrict__ dst,
                         const int* __restrict__ ls, const int* __restrict__ ld,
                         const int* __restrict__ off_t, const int* __restrict__ off_e,
                         const int* __restrict__ off_l,
                         int* __restrict__ cnt_t, int* __restrict__ cnt_e,
                         int* __restrict__ cnt_l,
                         int* __restrict__ adj_t, int* __restrict__ adj_e_m,
                         int* __restrict__ lperm_m, int* __restrict__ lsrc_m, int E, int L) {
  int i = blockIdx.x * blockDim.x + threadIdx.x;
  int st = gridDim.x * blockDim.x;
  int M = E > L ? E : L;
  for (; i < M; i += st) {
    if (i < E) {
      int s = src[i], d = dst[i];
      adj_t[off_t[d] + atomicSub(&cnt_t[d], 1) - 1] = s;
      adj_e_m[off_e[s] + atomicSub(&cnt_e[s], 1) - 1] = d;
    }
    if (i < L) {
      int d = ld[i];
      int p = off_l[d] + atomicSub(&cnt_l[d], 1) - 1;
      lperm_m[p] = i;
      lsrc_m[p] = ls[i];
    }
  }
}

// ---------------------------------------------------------------- pull mean (bf16 feats)
// one wave per node; lane handles one uint (2 bf16) of the 256B row; 4-deep gather ILP.
__global__ void pull_mean_bf16(const ushort_t* __restrict__ feat, const int* __restrict__ off,
                               const int* __restrict__ adj, ushort_t* __restrict__ out, int n) {
  int gid = blockIdx.x * blockDim.x + threadIdx.x;
  int wave = gid >> 6;
  int lane = gid & 63;
  int nw = (gridDim.x * blockDim.x) >> 6;
  const uint_t* f = (const uint_t*)feat;
  uint_t* o = (uint_t*)out;
  for (int v = wave; v < n; v += nw) {
    int s = off[v], e = off[v + 1];
    float ax0 = 0.f, ay0 = 0.f, ax1 = 0.f, ay1 = 0.f;
    float ax2 = 0.f, ay2 = 0.f, ax3 = 0.f, ay3 = 0.f;
    int i = s;
    for (; i + 4 <= e; i += 4) {
      uint_t u0 = f[(size_t)adj[i] * 64 + lane];
      uint_t u1 = f[(size_t)adj[i + 1] * 64 + lane];
      uint_t u2 = f[(size_t)adj[i + 2] * 64 + lane];
      uint_t u3 = f[(size_t)adj[i + 3] * 64 + lane];
      ax0 += bflo(u0); ay0 += bfhi(u0);
      ax1 += bflo(u1); ay1 += bfhi(u1);
      ax2 += bflo(u2); ay2 += bfhi(u2);
      ax3 += bflo(u3); ay3 += bfhi(u3);
    }
    for (; i < e; ++i) {
      uint_t u = f[(size_t)adj[i] * 64 + lane];
      ax0 += bflo(u); ay0 += bfhi(u);
    }
    float rd = 1.0f / fmaxf((float)(e - s), 1.0f);
    o[(size_t)v * 64 + lane] =
        (uint_t)f2bf(((ax0 + ax1) + (ax2 + ax3)) * rd) |
        ((uint_t)f2bf(((ay0 + ay1) + (ay2 + ay3)) * rd) << 16);
  }
}

// ---------------------------------------------------------------- MFMA GEMM (round-3 proven)
// out[row,:] = act( [agg[row,:] | xd[row,:]] @ [Wl;Wr] + bias ), bf16 in/out, fp32 accum.
template <bool RELU>
__global__ __launch_bounds__(256, 2) void gemm_mfma(
    const ushort_t* __restrict__ agg, const ushort_t* __restrict__ xd,
    const ushort_t* __restrict__ wfrag, const float* __restrict__ bias,
    ushort_t* __restrict__ out, int n) {
  __shared__ __align__(16) ushort_t sA[64 * 128];
  __shared__ __align__(16) ushort_t sX[64 * 128];
  const int t = threadIdx.x;
  const int lane = t & 63;
  const int wid = t >> 6;
  const int mrow = (wid >> 1) * 32;
  const int nhalf = (wid & 1) * 64;

  s16x8 B[8][4];
#pragma unroll
  for (int ks = 0; ks < 8; ++ks)
#pragma unroll
    for (int nfi = 0; nfi < 4; ++nfi)
      B[ks][nfi] = *(const s16x8*)(wfrag + (size_t)(((ks << 3) | ((nhalf >> 4) + nfi)) << 9) + (lane << 3));

  float bv[4];
#pragma unroll
  for (int nfi = 0; nfi < 4; ++nfi) bv[nfi] = bias[nhalf + nfi * 16 + (lane & 15)];

  const int lrow = lane >> 4;
  const int pbyte = (lane & 15) << 4;

  const int ntiles = (n + 63) >> 6;
  for (int tile = blockIdx.x; tile < ntiles; tile += gridDim.x) {
    const int row0 = tile << 6;
#pragma unroll
    for (int i = 0; i < 8; ++i) {
      int reg = (wid << 3) + i;
      int rr = ((reg & 15) << 2) + lrow;
      int row = row0 + rr;
      row = row < n ? row : n - 1;
      int pp = pbyte ^ ((rr & 7) << 4);
      const ushort_t* src = (reg < 16 ? agg : xd) + (size_t)row * H + (pp >> 1);
      ushort_t* ldst = (reg < 16 ? sA : sX) + ((reg & 15) << 9);
      gload_lds16(src, ldst);
    }
    __syncthreads();

    f32x4 acc[2][4];
#pragma unroll
    for (int mi = 0; mi < 2; ++mi)
#pragma unroll
      for (int nfi = 0; nfi < 4; ++nfi) {
        f32x4 c = {bv[nfi], bv[nfi], bv[nfi], bv[nfi]};
        acc[mi][nfi] = c;
      }

    const int rr0 = mrow + (lane & 15);
    const int rr1 = rr0 + 16;
    const int kx = (lane >> 4) << 4;
    const int sw = (rr0 & 7) << 4;
#pragma unroll
    for (int ks = 0; ks < 8; ++ks) {
      const ushort_t* base = (ks < 4) ? sA : sX;
      const int kb = (ks & 3) << 6;
      s16x8 a0 = *(const s16x8*)((const char*)base + rr0 * 256 + ((kb | kx) ^ sw));
      s16x8 a1 = *(const s16x8*)((const char*)base + rr1 * 256 + ((kb | kx) ^ sw));
#pragma unroll
      for (int nfi = 0; nfi < 4; ++nfi) {
        acc[0][nfi] = __builtin_amdgcn_mfma_f32_16x16x32_bf16(a0, B[ks][nfi], acc[0][nfi], 0, 0, 0);
        acc[1][nfi] = __builtin_amdgcn_mfma_f32_16x16x32_bf16(a1, B[ks][nfi], acc[1][nfi], 0, 0, 0);
      }
    }

#pragma unroll
    for (int mi = 0; mi < 2; ++mi) {
      int rbase = row0 + mrow + mi * 16 + ((lane >> 4) << 2);
#pragma unroll
      for (int r = 0; r < 4; ++r) {
        int row = rbase + r;
        if (row < n) {
#pragma unroll
          for (int nfi = 0; nfi < 4; ++nfi) {
            float v = acc[mi][nfi][r];
            if (RELU) v = fmaxf(v, 0.f);
            out[(size_t)row * H + nhalf + nfi * 16 + (lane & 15)] = f2bf(v);
          }
        }
      }
    }
    __syncthreads();
  }
}

// ---------------------------------------------------------------- grouped edge dot
// one wave per team: z_t row in registers, gather z_e rows per label; 4-deep ILP.
__global__ void edge_dot_grouped(const ushort_t* __restrict__ ze, const ushort_t* __restrict__ zt,
                                 const int* __restrict__ loff, const int* __restrict__ lperm,
                                 const int* __restrict__ lsrc, float* __restrict__ out, int n_t) {
  int gid = blockIdx.x * blockDim.x + threadIdx.x;
  int wave = gid >> 6;
  int lane = gid & 63;
  int nw = (gridDim.x * blockDim.x) >> 6;
  const uint_t* fz = (const uint_t*)ze;
  const uint_t* ft = (const uint_t*)zt;
  for (int v = wave; v < n_t; v += nw) {
    int s = loff[v], e = loff[v + 1];
    if (s == e) continue;
    uint_t ub = ft[(size_t)v * 64 + lane];
    float blo = bflo(ub), bhi = bfhi(ub);
    int i = s;
    for (; i + 4 <= e; i += 4) {
      uint_t u0 = fz[(size_t)lsrc[i] * 64 + lane];
      uint_t u1 = fz[(size_t)lsrc[i + 1] * 64 + lane];
      uint_t u2 = fz[(size_t)lsrc[i + 2] * 64 + lane];
      uint_t u3 = fz[(size_t)lsrc[i + 3] * 64 + lane];
      float p0 = bflo(u0) * blo + bfhi(u0) * bhi;
      float p1 = bflo(u1) * blo + bfhi(u1) * bhi;
      float p2 = bflo(u2) * blo + bfhi(u2) * bhi;
      float p3 = bflo(u3) * blo + bfhi(u3) * bhi;
#pragma unroll
      for (int o = 32; o; o >>= 1) {
        p0 += __shfl_down(p0, o);
        p1 += __shfl_down(p1, o);
        p2 += __shfl_down(p2, o);
        p3 += __shfl_down(p3, o);
      }
      if (lane == 0) {
        out[lperm[i]] = p0;
        out[lperm[i + 1]] = p1;
        out[lperm[i + 2]] = p2;
        out[lperm[i + 3]] = p3;
      }
    }
    for (; i < e; ++i) {
      uint_t u0 = fz[(size_t)lsrc[i] * 64 + lane];
      float p0 = bflo(u0) * blo + bfhi(u0) * bhi;
#pragma unroll
      for (int o = 32; o; o >>= 1) p0 += __shfl_down(p0, o);
      if (lane == 0) out[lperm[i]] = p0;
    }
  }
}

// ---------------------------------------------------------------- launch
extern "C" void kernel_launch(void* const* d_in, const int* in_sizes, int n_in,
                              void* d_out, int out_size, void* d_ws, size_t ws_size,
                              hipStream_t stream) {
  const float* x_e = (const float*)d_in[0];
  const float* x_t = (const float*)d_in[1];
  const int* src = (const int*)d_in[2];
  const int* dst = (const int*)d_in[3];
  const int* ls = (const int*)d_in[4];
  const int* ld = (const int*)d_in[5];
  const float* W1et_l = (const float*)d_in[6];
  const float* W1et_r = (const float*)d_in[7];
  const float* W1te_l = (const float*)d_in[8];
  const float* W1te_r = (const float*)d_in[9];
  const float* W2et_l = (const float*)d_in[10];
  const float* W2et_r = (const float*)d_in[11];
  const float* W2te_l = (const float*)d_in[12];
  const float* W2te_r = (const float*)d_in[13];
  const float* b1et = (const float*)d_in[14];
  const float* b1te = (const float*)d_in[15];
  const float* b2et = (const float*)d_in[16];
  const float* b2te = (const float*)d_in[17];

  const int n_e = in_sizes[0] / H;
  const int n_t = in_sizes[1] / H;
  const int E = in_sizes[2];
  const int L = in_sizes[4];
  float* out = (float*)d_out;

  const size_t fe = (size_t)n_e * H;
  const size_t ft = (size_t)n_t * H;
  ushort_t* us = (ushort_t*)d_ws;
  ushort_t* xb_e = us;               // fe
  ushort_t* xb_t = xb_e + fe;        // ft  (contiguous with xb_e for cvt2)
  ushort_t* agg_e = xb_t + ft;       // fe  (pull out; layer2: z_expert in place)
  ushort_t* agg_t = agg_e + fe;      // ft  (… z_team in place)
  ushort_t* h_e = agg_t + ft;        // fe
  ushort_t* h_t = h_e + fe;          // ft
  ushort_t* wfrag = h_t + ft;        // 4*32768 (order: 1et, 1te, 2et, 2te)
  int* ib = (int*)(wfrag + 4 * 32768);
  // concatenated counts: [cnt_t | cnt_e | cnt_l]
  const int Mt = n_t + 1, Me = n_e + 1, Ml = n_t + 1;
  const int M = Mt + Me + Ml;
  int* cnt = ib;               // M
  int* off = cnt + M;          // M   ([off_t | off_e(+E) | off_l(+2E)])
  int* part = off + M;         // 1024
  int* adj_t = part + 1024;    // E
  int* adj_e = adj_t + E;      // E
  int* lperm = adj_e + E;      // L
  int* lsrc = lperm + L;       // L

  int* cnt_t = cnt;
  int* cnt_e = cnt + Mt;
  int* cnt_l = cnt + Mt + Me;
  int* off_t = off;
  int* off_e = off + Mt;            // values in [E, 2E]
  int* off_l = off + Mt + Me;       // values in [2E, 2E+L]
  int* adj_e_m = adj_e - E;         // so adj_e_m[off_e[...]] lands in adj_e
  int* lperm_m = lperm - 2 * E;
  int* lsrc_m = lsrc - 2 * E;

  const dim3 blk(256);

  // ---- conversions + weight fragments
  cvt2_bf16<<<2048, blk, 0, stream>>>(x_e, x_t, fe / 4, (fe + ft) / 4, (uint2*)xb_e);
  build_wfrag4<<<512, blk, 0, stream>>>(W1et_l, W1et_r, W1te_l, W1te_r,
                                        W2et_l, W2et_r, W2te_l, W2te_r, wfrag);

  // ---- merged CSR build (edges + labels), single concatenated scan
  zero_i32<<<256, blk, 0, stream>>>(cnt, M);
  hist_all<<<1024, blk, 0, stream>>>(src, dst, ld, cnt_t, cnt_e, cnt_l, E, L);
  int nb = (M + 255) / 256;
  scan1<<<nb, blk, 0, stream>>>(cnt, off, part, M);
  scan2<<<1, blk, 0, stream>>>(part, nb);
  scan3<<<nb, blk, 0, stream>>>(off, part, M);
  fill_all<<<1024, blk, 0, stream>>>(src, dst, ls, ld, off_t, off_e, off_l,
                                     cnt_t, cnt_e, cnt_l,
                                     adj_t, adj_e_m, lperm_m, lsrc_m, E, L);

  const int gt = min((n_t + 63) / 64, 512);
  const int ge = min((n_e + 63) / 64, 512);

  // ---- layer 1
  pull_mean_bf16<<<(n_t + 3) / 4, blk, 0, stream>>>(xb_e, off_t, adj_t, agg_t, n_t);
  pull_mean_bf16<<<(n_e + 3) / 4, blk, 0, stream>>>(xb_t, off_e, adj_e_m, agg_e, n_e);
  gemm_mfma<true><<<gt, blk, 0, stream>>>(agg_t, xb_t, wfrag + 0 * 32768, b1et, h_t, n_t);
  gemm_mfma<true><<<ge, blk, 0, stream>>>(agg_e, xb_e, wfrag + 1 * 32768, b1te, h_e, n_e);

  // ---- layer 2 (z written in place over agg)
  pull_mean_bf16<<<(n_t + 3) / 4, blk, 0, stream>>>(h_e, off_t, adj_t, agg_t, n_t);
  pull_mean_bf16<<<(n_e + 3) / 4, blk, 0, stream>>>(h_t, off_e, adj_e_m, agg_e, n_e);
  gemm_mfma<false><<<gt, blk, 0, stream>>>(agg_t, h_t, wfrag + 2 * 32768, b2et, agg_t, n_t);
  gemm_mfma<false><<<ge, blk, 0, stream>>>(agg_e, h_e, wfrag + 3 * 32768, b2te, agg_e, n_e);

  // ---- grouped edge dot readout
  edge_dot_grouped<<<(n_t + 3) / 4, blk, 0, stream>>>(agg_e, agg_t, off_l, lperm_m, lsrc_m, out, n_t);
}

// Round 6
// 449.569 us; speedup vs baseline: 1.7001x; 1.0348x over previous
//
#include <hip/hip_runtime.h>

#define H 128
typedef unsigned short ushort_t;
typedef unsigned int uint_t;
using s16x8 = __attribute__((ext_vector_type(8))) short;
using f32x4 = __attribute__((ext_vector_type(4))) float;

// ---------------------------------------------------------------- bf16 helpers
__device__ __forceinline__ ushort_t f2bf(float x) {  // RNE
  uint_t u = __float_as_uint(x);
  return (ushort_t)((u + 0x7fff + ((u >> 16) & 1)) >> 16);
}
__device__ __forceinline__ float bflo(uint_t u) { return __uint_as_float(u << 16); }
__device__ __forceinline__ float bfhi(uint_t u) { return __uint_as_float(u & 0xffff0000u); }

// ---------------------------------------------------------------- async global->LDS 16B
__device__ __forceinline__ void gload_lds16(const void* g, void* l) {
  __builtin_amdgcn_global_load_lds(
      (const __attribute__((address_space(1))) unsigned int*)(unsigned long long)g,
      (__attribute__((address_space(3))) unsigned int*)(unsigned int)(unsigned long long)l,
      16, 0, 0);
}

// ---------------------------------------------------------------- zero ints
__global__ void zero_i32(int* __restrict__ p, int n) {
  int i = blockIdx.x * blockDim.x + threadIdx.x;
  int s = gridDim.x * blockDim.x;
  for (; i < n; i += s) p[i] = 0;
}

// ---------------------------------------------------------------- fp32 -> bf16 (two srcs, contiguous dst)
__global__ void cvt2_bf16(const float* __restrict__ a, const float* __restrict__ b,
                          size_t n4a, size_t n4tot, uint2* __restrict__ out) {
  size_t i = (size_t)blockIdx.x * blockDim.x + threadIdx.x;
  size_t s = (size_t)gridDim.x * blockDim.x;
  for (; i < n4tot; i += s) {
    float4 v = (i < n4a) ? ((const float4*)a)[i] : ((const float4*)b)[i - n4a];
    uint2 r;
    r.x = (uint_t)f2bf(v.x) | ((uint_t)f2bf(v.y) << 16);
    r.y = (uint_t)f2bf(v.z) | ((uint_t)f2bf(v.w) << 16);
    out[i] = r;
  }
}

// ------------------------------------------- 4 W-pairs -> MFMA B-fragment layout
__global__ void build_wfrag4(const float* __restrict__ Wl0, const float* __restrict__ Wr0,
                             const float* __restrict__ Wl1, const float* __restrict__ Wr1,
                             const float* __restrict__ Wl2, const float* __restrict__ Wr2,
                             const float* __restrict__ Wl3, const float* __restrict__ Wr3,
                             ushort_t* __restrict__ dst) {
  int i = blockIdx.x * 256 + threadIdx.x;  // 0..131071
  int w = i >> 15;
  int ii = i & 32767;
  int j = ii & 7;
  int lane = (ii >> 3) & 63;
  int nf = (ii >> 9) & 7;
  int ks = ii >> 12;
  int k = ks * 32 + (lane >> 4) * 8 + j;
  int nn = nf * 16 + (lane & 15);
  const float* Wl = (w == 0) ? Wl0 : (w == 1) ? Wl1 : (w == 2) ? Wl2 : Wl3;
  const float* Wr = (w == 0) ? Wr0 : (w == 1) ? Wr1 : (w == 2) ? Wr2 : Wr3;
  float v = (k < H) ? Wl[k * H + nn] : Wr[(k - H) * H + nn];
  dst[i] = f2bf(v);
}

// ---------------------------------------------------------------- merged histogram (edges + labels)
__global__ void hist_all(const int* __restrict__ src, const int* __restrict__ dst,
                         const int* __restrict__ ld,
                         int* __restrict__ cnt_t, int* __restrict__ cnt_e,
                         int* __restrict__ cnt_l, int E, int L) {
  int i = blockIdx.x * blockDim.x + threadIdx.x;
  int s = gridDim.x * blockDim.x;
  int M = E > L ? E : L;
  for (; i < M; i += s) {
    if (i < E) {
      atomicAdd(&cnt_t[dst[i]], 1);
      atomicAdd(&cnt_e[src[i]], 1);
    }
    if (i < L) atomicAdd(&cnt_l[ld[i]], 1);
  }
}

// ---------------------------------------------------------------- 3-phase exclusive scan
__global__ void scan1(const int* __restrict__ in, int* __restrict__ out,
                      int* __restrict__ part, int n) {
  __shared__ int s[256];
  int t = threadIdx.x;
  int i = blockIdx.x * 256 + t;
  int v = (i < n) ? in[i] : 0;
  s[t] = v;
  __syncthreads();
  for (int off = 1; off < 256; off <<= 1) {
    int tmp = (t >= off) ? s[t - off] : 0;
    __syncthreads();
    s[t] += tmp;
    __syncthreads();
  }
  if (i < n) out[i] = s[t] - v;
  if (t == 255) part[blockIdx.x] = s[255];
}

__global__ void scan2(int* __restrict__ part, int nb) {
  __shared__ int s[256];
  __shared__ int carry;
  int t = threadIdx.x;
  if (t == 0) carry = 0;
  __syncthreads();
  for (int base = 0; base < nb; base += 256) {
    int i = base + t;
    int v = (i < nb) ? part[i] : 0;
    s[t] = v;
    __syncthreads();
    for (int off = 1; off < 256; off <<= 1) {
      int tmp = (t >= off) ? s[t - off] : 0;
      __syncthreads();
      s[t] += tmp;
      __syncthreads();
    }
    if (i < nb) part[i] = s[t] - v + carry;
    __syncthreads();
    if (t == 255) carry += s[255];
    __syncthreads();
  }
}

__global__ void scan3(int* __restrict__ out, const int* __restrict__ part, int n) {
  int i = blockIdx.x * 256 + threadIdx.x;
  if (i < n) out[i] += part[blockIdx.x];
}

// ---------------------------------------------------------------- merged fill (edges + labels)
// NT stores: scattered 4/8B writes bypass per-XCD L2 so partial lines merge memory-side.
__global__ void fill_all(const int* __restrict__ src, const int* __restrict__ dst,
                         const int* __restrict__ ls, const int* __restrict__ ld,
                         const int* __restrict__ off_t, const int* __restrict__ off_e,
                         const int* __restrict__ off_l,
                         int* __restrict__ cnt_t, int* __restrict__ cnt_e,
                         int* __restrict__ cnt_l,
                         int* __restrict__ adj_t, int* __restrict__ adj_e_m,
                         long long* __restrict__ lpair_m, int E, int L) {
  int i = blockIdx.x * blockDim.x + threadIdx.x;
  int st = gridDim.x * blockDim.x;
  int M = E > L ? E : L;
  for (; i < M; i += st) {
    if (i < E) {
      int s = src[i], d = dst[i];
      int pt = off_t[d] + atomicSub(&cnt_t[d], 1) - 1;
      __builtin_nontemporal_store(s, &adj_t[pt]);
      int pe = off_e[s] + atomicSub(&cnt_e[s], 1) - 1;
      __builtin_nontemporal_store(d, &adj_e_m[pe]);
    }
    if (i < L) {
      int d = ld[i];
      int p = off_l[d] + atomicSub(&cnt_l[d], 1) - 1;
      long long pr = ((long long)ls[i] << 32) | (unsigned int)i;
      __builtin_nontemporal_store(pr, &lpair_m[p]);
    }
  }
}

// ---------------------------------------------------------------- dual pull mean (bf16 feats)
// one wave per node over both node sets; lane handles one uint (2 bf16); 4-deep gather ILP.
__global__ void pull_mean_dual(
    const ushort_t* __restrict__ featA, const int* __restrict__ offA, const int* __restrict__ adjA,
    ushort_t* __restrict__ outA, int nA,
    const ushort_t* __restrict__ featB, const int* __restrict__ offB, const int* __restrict__ adjB,
    ushort_t* __restrict__ outB, int nB) {
  int gid = blockIdx.x * blockDim.x + threadIdx.x;
  int wave = gid >> 6;
  int lane = gid & 63;
  int nw = (gridDim.x * blockDim.x) >> 6;
  for (int v = wave; v < nA + nB; v += nw) {
    const uint_t* f;
    const int* off;
    const int* adj;
    uint_t* o;
    int vv;
    if (v < nA) {
      f = (const uint_t*)featA; off = offA; adj = adjA; o = (uint_t*)outA; vv = v;
    } else {
      f = (const uint_t*)featB; off = offB; adj = adjB; o = (uint_t*)outB; vv = v - nA;
    }
    int s = off[vv], e = off[vv + 1];
    float ax0 = 0.f, ay0 = 0.f, ax1 = 0.f, ay1 = 0.f;
    float ax2 = 0.f, ay2 = 0.f, ax3 = 0.f, ay3 = 0.f;
    int i = s;
    for (; i + 4 <= e; i += 4) {
      uint_t u0 = f[(size_t)adj[i] * 64 + lane];
      uint_t u1 = f[(size_t)adj[i + 1] * 64 + lane];
      uint_t u2 = f[(size_t)adj[i + 2] * 64 + lane];
      uint_t u3 = f[(size_t)adj[i + 3] * 64 + lane];
      ax0 += bflo(u0); ay0 += bfhi(u0);
      ax1 += bflo(u1); ay1 += bfhi(u1);
      ax2 += bflo(u2); ay2 += bfhi(u2);
      ax3 += bflo(u3); ay3 += bfhi(u3);
    }
    for (; i < e; ++i) {
      uint_t u = f[(size_t)adj[i] * 64 + lane];
      ax0 += bflo(u); ay0 += bfhi(u);
    }
    float rd = 1.0f / fmaxf((float)(e - s), 1.0f);
    o[(size_t)vv * 64 + lane] =
        (uint_t)f2bf(((ax0 + ax1) + (ax2 + ax3)) * rd) |
        ((uint_t)f2bf(((ay0 + ay1) + (ay2 + ay3)) * rd) << 16);
  }
}

// ---------------------------------------------------------------- dual MFMA GEMM
// blocks [0,gA): side A; [gA,grid): side B. B-fragments register-resident per block.
template <bool RELU>
__global__ __launch_bounds__(256, 2) void gemm_mfma_dual(
    const ushort_t* __restrict__ aggA, const ushort_t* __restrict__ xdA,
    const ushort_t* __restrict__ wfA, const float* __restrict__ biasA,
    ushort_t* __restrict__ outA, int nA, int gA,
    const ushort_t* __restrict__ aggB, const ushort_t* __restrict__ xdB,
    const ushort_t* __restrict__ wfB, const float* __restrict__ biasB,
    ushort_t* __restrict__ outB, int nB) {
  __shared__ __align__(16) ushort_t sA[64 * 128];
  __shared__ __align__(16) ushort_t sX[64 * 128];
  const ushort_t *agg, *xd, *wfrag;
  const float* bias;
  ushort_t* outp;
  int n, b0, nbl;
  if ((int)blockIdx.x < gA) {
    agg = aggA; xd = xdA; wfrag = wfA; bias = biasA; outp = outA; n = nA;
    b0 = blockIdx.x; nbl = gA;
  } else {
    agg = aggB; xd = xdB; wfrag = wfB; bias = biasB; outp = outB; n = nB;
    b0 = blockIdx.x - gA; nbl = gridDim.x - gA;
  }
  const int t = threadIdx.x;
  const int lane = t & 63;
  const int wid = t >> 6;
  const int mrow = (wid >> 1) * 32;
  const int nhalf = (wid & 1) * 64;

  s16x8 B[8][4];
#pragma unroll
  for (int ks = 0; ks < 8; ++ks)
#pragma unroll
    for (int nfi = 0; nfi < 4; ++nfi)
      B[ks][nfi] = *(const s16x8*)(wfrag + (size_t)(((ks << 3) | ((nhalf >> 4) + nfi)) << 9) + (lane << 3));

  float bv[4];
#pragma unroll
  for (int nfi = 0; nfi < 4; ++nfi) bv[nfi] = bias[nhalf + nfi * 16 + (lane & 15)];

  const int lrow = lane >> 4;
  const int pbyte = (lane & 15) << 4;

  const int ntiles = (n + 63) >> 6;
  for (int tile = b0; tile < ntiles; tile += nbl) {
    const int row0 = tile << 6;
#pragma unroll
    for (int i = 0; i < 8; ++i) {
      int reg = (wid << 3) + i;
      int rr = ((reg & 15) << 2) + lrow;
      int row = row0 + rr;
      row = row < n ? row : n - 1;
      int pp = pbyte ^ ((rr & 7) << 4);
      const ushort_t* srcp = (reg < 16 ? agg : xd) + (size_t)row * H + (pp >> 1);
      ushort_t* ldst = (reg < 16 ? sA : sX) + ((reg & 15) << 9);
      gload_lds16(srcp, ldst);
    }
    __syncthreads();

    f32x4 acc[2][4];
#pragma unroll
    for (int mi = 0; mi < 2; ++mi)
#pragma unroll
      for (int nfi = 0; nfi < 4; ++nfi) {
        f32x4 c = {bv[nfi], bv[nfi], bv[nfi], bv[nfi]};
        acc[mi][nfi] = c;
      }

    const int rr0 = mrow + (lane & 15);
    const int rr1 = rr0 + 16;
    const int kx = (lane >> 4) << 4;
    const int sw = (rr0 & 7) << 4;
#pragma unroll
    for (int ks = 0; ks < 8; ++ks) {
      const ushort_t* base = (ks < 4) ? sA : sX;
      const int kb = (ks & 3) << 6;
      s16x8 a0 = *(const s16x8*)((const char*)base + rr0 * 256 + ((kb | kx) ^ sw));
      s16x8 a1 = *(const s16x8*)((const char*)base + rr1 * 256 + ((kb | kx) ^ sw));
#pragma unroll
      for (int nfi = 0; nfi < 4; ++nfi) {
        acc[0][nfi] = __builtin_amdgcn_mfma_f32_16x16x32_bf16(a0, B[ks][nfi], acc[0][nfi], 0, 0, 0);
        acc[1][nfi] = __builtin_amdgcn_mfma_f32_16x16x32_bf16(a1, B[ks][nfi], acc[1][nfi], 0, 0, 0);
      }
    }

#pragma unroll
    for (int mi = 0; mi < 2; ++mi) {
      int rbase = row0 + mrow + mi * 16 + ((lane >> 4) << 2);
#pragma unroll
      for (int r = 0; r < 4; ++r) {
        int row = rbase + r;
        if (row < n) {
#pragma unroll
          for (int nfi = 0; nfi < 4; ++nfi) {
            float v = acc[mi][nfi][r];
            if (RELU) v = fmaxf(v, 0.f);
            outp[(size_t)row * H + nhalf + nfi * 16 + (lane & 15)] = f2bf(v);
          }
        }
      }
    }
    __syncthreads();
  }
}

// ---------------------------------------------------------------- grouped edge dot
// one wave per team: z_t row in registers; packed (perm|src) labels; NT scattered out.
__global__ void edge_dot_grouped(const ushort_t* __restrict__ ze, const ushort_t* __restrict__ zt,
                                 const int* __restrict__ loff, const long long* __restrict__ lpair,
                                 float* __restrict__ out, int n_t) {
  int gid = blockIdx.x * blockDim.x + threadIdx.x;
  int wave = gid >> 6;
  int lane = gid & 63;
  int nw = (gridDim.x * blockDim.x) >> 6;
  const uint_t* fz = (const uint_t*)ze;
  const uint_t* ft = (const uint_t*)zt;
  for (int v = wave; v < n_t; v += nw) {
    int s = loff[v], e = loff[v + 1];
    if (s == e) continue;
    uint_t ub = ft[(size_t)v * 64 + lane];
    float blo = bflo(ub), bhi = bfhi(ub);
    int i = s;
    for (; i + 4 <= e; i += 4) {
      long long q0 = lpair[i], q1 = lpair[i + 1], q2 = lpair[i + 2], q3 = lpair[i + 3];
      uint_t u0 = fz[(size_t)(int)(q0 >> 32) * 64 + lane];
      uint_t u1 = fz[(size_t)(int)(q1 >> 32) * 64 + lane];
      uint_t u2 = fz[(size_t)(int)(q2 >> 32) * 64 + lane];
      uint_t u3 = fz[(size_t)(int)(q3 >> 32) * 64 + lane];
      float p0 = bflo(u0) * blo + bfhi(u0) * bhi;
      float p1 = bflo(u1) * blo + bfhi(u1) * bhi;
      float p2 = bflo(u2) * blo + bfhi(u2) * bhi;
      float p3 = bflo(u3) * blo + bfhi(u3) * bhi;
#pragma unroll
      for (int o = 32; o; o >>= 1) {
        p0 += __shfl_down(p0, o);
        p1 += __shfl_down(p1, o);
        p2 += __shfl_down(p2, o);
        p3 += __shfl_down(p3, o);
      }
      if (lane == 0) {
        __builtin_nontemporal_store(p0, &out[(int)q0]);
        __builtin_nontemporal_store(p1, &out[(int)q1]);
        __builtin_nontemporal_store(p2, &out[(int)q2]);
        __builtin_nontemporal_store(p3, &out[(int)q3]);
      }
    }
    for (; i < e; ++i) {
      long long q0 = lpair[i];
      uint_t u0 = fz[(size_t)(int)(q0 >> 32) * 64 + lane];
      float p0 = bflo(u0) * blo + bfhi(u0) * bhi;
#pragma unroll
      for (int o = 32; o; o >>= 1) p0 += __shfl_down(p0, o);
      if (lane == 0) __builtin_nontemporal_store(p0, &out[(int)q0]);
    }
  }
}

// ---------------------------------------------------------------- launch
extern "C" void kernel_launch(void* const* d_in, const int* in_sizes, int n_in,
                              void* d_out, int out_size, void* d_ws, size_t ws_size,
                              hipStream_t stream) {
  const float* x_e = (const float*)d_in[0];
  const float* x_t = (const float*)d_in[1];
  const int* src = (const int*)d_in[2];
  const int* dst = (const int*)d_in[3];
  const int* ls = (const int*)d_in[4];
  const int* ld = (const int*)d_in[5];
  const float* W1et_l = (const float*)d_in[6];
  const float* W1et_r = (const float*)d_in[7];
  const float* W1te_l = (const float*)d_in[8];
  const float* W1te_r = (const float*)d_in[9];
  const float* W2et_l = (const float*)d_in[10];
  const float* W2et_r = (const float*)d_in[11];
  const float* W2te_l = (const float*)d_in[12];
  const float* W2te_r = (const float*)d_in[13];
  const float* b1et = (const float*)d_in[14];
  const float* b1te = (const float*)d_in[15];
  const float* b2et = (const float*)d_in[16];
  const float* b2te = (const float*)d_in[17];

  const int n_e = in_sizes[0] / H;
  const int n_t = in_sizes[1] / H;
  const int E = in_sizes[2];
  const int L = in_sizes[4];
  float* out = (float*)d_out;

  const size_t fe = (size_t)n_e * H;
  const size_t ft = (size_t)n_t * H;
  ushort_t* us = (ushort_t*)d_ws;
  ushort_t* xb_e = us;               // fe
  ushort_t* xb_t = xb_e + fe;        // ft  (contiguous with xb_e for cvt2)
  ushort_t* agg_e = xb_t + ft;       // fe  (layer2: z_expert in place)
  ushort_t* agg_t = agg_e + fe;      // ft  (… z_team in place)
  ushort_t* h_e = agg_t + ft;        // fe
  ushort_t* h_t = h_e + fe;          // ft
  ushort_t* wfrag = h_t + ft;        // 4*32768 (order: 1et, 1te, 2et, 2te)
  int* ib = (int*)(wfrag + 4 * 32768);
  const int Mt = n_t + 1, Me = n_e + 1, Ml = n_t + 1;
  const int M = Mt + Me + Ml;
  int* cnt = ib;               // M   ([cnt_t | cnt_e | cnt_l])
  int* off = cnt + M;          // M   ([off_t | off_e(+E) | off_l(+2E)])
  int* part = off + M;         // 1024
  int* adj_t = part + 1024;    // E
  int* adj_e = adj_t + E;      // E
  long long* lpair = (long long*)(((unsigned long long)(adj_e + E) + 7) & ~7ULL);  // L x 8B

  int* cnt_t = cnt;
  int* cnt_e = cnt + Mt;
  int* cnt_l = cnt + Mt + Me;
  int* off_t = off;
  int* off_e = off + Mt;            // values in [E, 2E]
  int* off_l = off + Mt + Me;       // values in [2E, 2E+L]
  int* adj_e_m = adj_e - E;
  long long* lpair_m = lpair - 2 * (size_t)E;

  const dim3 blk(256);

  // ---- conversions + weight fragments
  cvt2_bf16<<<2048, blk, 0, stream>>>(x_e, x_t, fe / 4, (fe + ft) / 4, (uint2*)xb_e);
  build_wfrag4<<<512, blk, 0, stream>>>(W1et_l, W1et_r, W1te_l, W1te_r,
                                        W2et_l, W2et_r, W2te_l, W2te_r, wfrag);

  // ---- merged CSR build (edges + labels), single concatenated scan
  zero_i32<<<256, blk, 0, stream>>>(cnt, M);
  hist_all<<<1024, blk, 0, stream>>>(src, dst, ld, cnt_t, cnt_e, cnt_l, E, L);
  int nb = (M + 255) / 256;
  scan1<<<nb, blk, 0, stream>>>(cnt, off, part, M);
  scan2<<<1, blk, 0, stream>>>(part, nb);
  scan3<<<nb, blk, 0, stream>>>(off, part, M);
  fill_all<<<1024, blk, 0, stream>>>(src, dst, ls, ld, off_t, off_e, off_l,
                                     cnt_t, cnt_e, cnt_l,
                                     adj_t, adj_e_m, lpair_m, E, L);

  const int gt = (n_t + 63) / 64, ge = (n_e + 63) / 64;
  const int gA = min(gt, 512), gB = min(ge, 512);
  const int npull = ((n_t + n_e) + 3) / 4;

  // ---- layer 1
  pull_mean_dual<<<npull, blk, 0, stream>>>(xb_e, off_t, adj_t, agg_t, n_t,
                                            xb_t, off_e, adj_e_m, agg_e, n_e);
  gemm_mfma_dual<true><<<gA + gB, blk, 0, stream>>>(
      agg_t, xb_t, wfrag + 0 * 32768, b1et, h_t, n_t, gA,
      agg_e, xb_e, wfrag + 1 * 32768, b1te, h_e, n_e);

  // ---- layer 2 (z written in place over agg)
  pull_mean_dual<<<npull, blk, 0, stream>>>(h_e, off_t, adj_t, agg_t, n_t,
                                            h_t, off_e, adj_e_m, agg_e, n_e);
  gemm_mfma_dual<false><<<gA + gB, blk, 0, stream>>>(
      agg_t, h_t, wfrag + 2 * 32768, b2et, agg_t, n_t, gA,
      agg_e, h_e, wfrag + 3 * 32768, b2te, agg_e, n_e);

  // ---- grouped edge dot readout
  edge_dot_grouped<<<(n_t + 3) / 4, blk, 0, stream>>>(agg_e, agg_t, off_l, lpair_m, out, n_t);
}